// Round 9
// baseline (2292.162 us; speedup 1.0000x reference)
//
#include <hip/hip_runtime.h>
#include <math.h>

#define B_ 64
#define T_ 512
#define H_ 1024
#define V_ 256
#define O_ 1024
#define KFC 2048

typedef short bf16x8 __attribute__((ext_vector_type(8)));
typedef _Float16 f16x8 __attribute__((ext_vector_type(8)));
typedef float f32x4 __attribute__((ext_vector_type(4)));
typedef int   i32x4 __attribute__((ext_vector_type(4)));
typedef unsigned long long u64x2 __attribute__((ext_vector_type(2)));

#define FLIP64 0x8000800080008000ULL

// ---- workspace layout (bytes) ----
#define OFF_TABLE_F 0                 // [V][H] f32 (W_ih^T + b_ih + b_hh), fwd
#define OFF_TABLE_B 1048576           // same, bwd
#define OFF_XT      2097152           // [T][B] i32 (transposed x)
#define OFF_WHH     2228224           // fp16 [d][cs16][ct4][kt32][lane64][8] (4 MB)
#define OFF_WFC     6422528           // fp16 [ob][k32][nt][lane][8] (4 MB)
#define OFF_HSF     10616832          // fp16 frag, sign-flipped: [t][bt][kt][q][lane'] u64 (64 MB)
#define OFF_HSB     77725696          // same, bwd (64 MB)  — adjacent to HSF

// ---------------- prep: tables, transposes, packed weights, hs zeroing ----------------
__global__ void prep_kernel(const int* __restrict__ x,
    const float* __restrict__ WihF, const float* __restrict__ WhhF,
    const float* __restrict__ bihF, const float* __restrict__ bhhF,
    const float* __restrict__ WihB, const float* __restrict__ WhhB,
    const float* __restrict__ bihB, const float* __restrict__ bhhB,
    const float* __restrict__ Wfc,
    float* __restrict__ tableF, float* __restrict__ tableB,
    int* __restrict__ xT, short* __restrict__ whhpack,
    short* __restrict__ wfcpack, unsigned long long* __restrict__ hsz)
{
  const long NT1 = 524288, NT2 = 32768, NT3 = 2097152, NT4 = 2097152;
  const long NT5 = 16777216;  // zero hsF+hsB (adjacent, 128 MB) as u64
  const long total = NT1 + NT2 + NT3 + NT4 + NT5;
  for (long i = (long)blockIdx.x * blockDim.x + threadIdx.x; i < total;
       i += (long)gridDim.x * blockDim.x) {
    long j = i;
    if (j < NT1) {
      int d = (int)(j >> 18);
      int r = (int)(j & 262143);
      int v = r >> 10, h = r & 1023;
      const float* Wih = d ? WihB : WihF;
      const float* bi  = d ? bihB : bihF;
      const float* bh  = d ? bhhB : bhhF;
      (d ? tableB : tableF)[r] = Wih[h * V_ + v] + bi[h] + bh[h];
      continue;
    }
    j -= NT1;
    if (j < NT2) {
      int t = (int)(j >> 6), bb = (int)(j & 63);
      xT[j] = x[bb * T_ + t];
      continue;
    }
    j -= NT2;
    if (j < NT3) {
      // whhpack [d][cs16][ct4][kt32][lane64][8]:
      //   c = cs*64 + ct*16 + (lane&15), k = kt*32 + (lane>>4)*8 + jj
      int d = (int)(j >> 20);
      int r = (int)(j & 1048575);
      int jj = r & 7;
      int lanei = (r >> 3) & 63;
      int kt = (r >> 9) & 31;
      int cti = (r >> 14) & 3;
      int csi = (r >> 16) & 15;
      int c = csi * 64 + cti * 16 + (lanei & 15);
      int k = kt * 32 + (lanei >> 4) * 8 + jj;
      float w = (d ? WhhB : WhhF)[c * H_ + k];
      _Float16 wh = (_Float16)w;
      whhpack[j] = __builtin_bit_cast(short, wh);
      continue;
    }
    j -= NT3;
    if (j < NT4) {
      int jj = (int)(j & 7);
      int lanei = (int)((j >> 3) & 63);
      int nti = (int)((j >> 9) & 3);
      int k32 = (int)((j >> 11) & 63);
      int obi = (int)(j >> 17);
      int o = obi * 64 + nti * 16 + (lanei & 15);
      int k = k32 * 32 + (lanei >> 4) * 8 + jj;
      _Float16 wf = (_Float16)Wfc[(long)o * KFC + k];
      wfcpack[j] = __builtin_bit_cast(short, wf);
      continue;
    }
    j -= NT4;
    hsz[j] = 0ULL;  // unwritten sentinel for the self-signaling exchange
    continue;
  }
}

// ---------------- persistent bidirectional recurrence ----------------
// 128 WGs x 256 thr. WG = (dir, bt 16-row tile, cs 64-col slice); wave = ct.
// BARRIER-FREE steps: every wave loads its B-fragments DIRECTLY from the
// self-signaling exchange (fragment layout, 512B-coalesced per instruction);
// the fragment load IS the poll (u64 nonzero == written). k processed in
// 4 groups of 8 kt through two register banks, software-pipelined so group
// g+1's L3 RTT hides under group g's poll+MFMA. No LDS h staging, no
// barriers, no flags, no fences; waves fully decoupled.
__global__ __launch_bounds__(256, 1)
void rnn_kernel(const int* __restrict__ xT,
                const float* __restrict__ tableF, const float* __restrict__ tableB,
                const short* __restrict__ whhpack,
                unsigned long long* __restrict__ hsfF,
                unsigned long long* __restrict__ hsfB)
{
  extern __shared__ char lds[];   // 128 KB: W frags [ct][kt][lane][16B]
  char* ldsW = lds;
  const int tid = threadIdx.x;
  const int wg = blockIdx.x;
  const int dir = wg >> 6;
  const int bt = (wg >> 4) & 3;
  const int cs = wg & 15;
  const int lane = tid & 63;
  const int ct = tid >> 6;
  const int row = bt * 16 + (lane & 15);               // my batch row
  const int c4 = cs * 64 + ct * 16 + (lane >> 4) * 4;  // my 4 output cols
  const float* table = dir ? tableB : tableF;
  unsigned long long* hsx = dir ? hsfB : hsfF;
  const int pub_off = bt * 4096 + (c4 >> 5) * 128 + ((c4 >> 2) & 1) * 64 +
                      (lane & 15) + ((c4 >> 3) & 3) * 16;

  // one-time: W slice (my 64 cols) -> LDS, fragment-linear
  {
    const i32x4* wsrc = (const i32x4*)whhpack + (size_t)(dir * 16 + cs) * 8192;
    i32x4* wdst = (i32x4*)ldsW;
    #pragma unroll
    for (int it = 0; it < 32; ++it)
      wdst[it * 256 + tid] = wsrc[it * 256 + tid];
  }
  __syncthreads();

  const f32x4 zv = {0.f, 0.f, 0.f, 0.f};

  // ---- prologue: step 0 (h_0 = tanh(xw)) ----
  {
    int t0 = dir ? 511 : 0;
    int v = xT[t0 * 64 + row];
    f32x4 xwv = *(const f32x4*)(table + v * 1024 + c4);
    unsigned long long hx = 0;
    #pragma unroll
    for (int r = 0; r < 4; ++r) {
      float e = __expf(2.0f * xwv[r]);
      float h = (e - 1.0f) / (e + 1.0f);
      union { _Float16 f; unsigned short u; } cv; cv.f = (_Float16)h;
      unsigned short u = (cv.u == 0x8000u) ? 0u : cv.u;  // -0 -> +0
      hx |= (unsigned long long)(u ^ 0x8000u) << (16 * r);  // field never 0
    }
    __hip_atomic_store(hsx + (size_t)t0 * 16384 + pub_off, hx,
                       __ATOMIC_RELAXED, __HIP_MEMORY_SCOPE_AGENT);
  }

  for (int s = 1; s < 512; ++s) {
    const int t = dir ? (511 - s) : s;
    const int tprev = dir ? (t + 1) : (t - 1);
    // xw gather early (independent)
    int v = xT[t * 64 + row];
    f32x4 xwv = *(const f32x4*)(table + v * 1024 + c4);

    // B-fragment base for h_{s-1}: per-lane fragment-direct, 512B-coalesced
    const unsigned long long* sp =
        hsx + (size_t)tprev * 16384 + bt * 4096 + lane;

    f32x4 acc4[4] = {zv, zv, zv, zv};
    unsigned long long A0[8], B0[8], A1[8], B1[8];

#define ISSUEG(g, A, B) do { \
    _Pragma("unroll") \
    for (int i = 0; i < 8; ++i) { \
      (A)[i] = __hip_atomic_load(sp + ((g) * 8 + i) * 128, \
                                 __ATOMIC_RELAXED, __HIP_MEMORY_SCOPE_AGENT); \
      (B)[i] = __hip_atomic_load(sp + ((g) * 8 + i) * 128 + 64, \
                                 __ATOMIC_RELAXED, __HIP_MEMORY_SCOPE_AGENT); \
    } \
  } while (0)

#define POLLG(g, A, B) do { \
    for (;;) { \
      int miss = 0; \
      _Pragma("unroll") \
      for (int i = 0; i < 8; ++i) \
        miss |= ((A)[i] == 0ULL) | ((B)[i] == 0ULL); \
      if (!__ballot(miss)) break; \
      __builtin_amdgcn_s_sleep(1); \
      ISSUEG(g, A, B); \
    } \
  } while (0)

#define MFMAG(g, A, B) do { \
    _Pragma("unroll") \
    for (int i = 0; i < 8; ++i) { \
      int kt = (g) * 8 + i; \
      f16x8 af = *(const f16x8*)(ldsW + ((ct * 32 + kt) * 64 + lane) * 16); \
      u64x2 bv; bv[0] = (A)[i] ^ FLIP64; bv[1] = (B)[i] ^ FLIP64; \
      f16x8 bf = __builtin_bit_cast(f16x8, bv); \
      acc4[i & 3] = \
          __builtin_amdgcn_mfma_f32_16x16x32_f16(af, bf, acc4[i & 3], 0, 0, 0); \
    } \
  } while (0)

    ISSUEG(0, A0, B0);
    ISSUEG(1, A1, B1);
    POLLG(0, A0, B0);
    MFMAG(0, A0, B0);
    ISSUEG(2, A0, B0);
    POLLG(1, A1, B1);
    MFMAG(1, A1, B1);
    ISSUEG(3, A1, B1);
    POLLG(2, A0, B0);
    MFMAG(2, A0, B0);
    POLLG(3, A1, B1);
    MFMAG(3, A1, B1);

#undef ISSUEG
#undef POLLG
#undef MFMAG

    // epilogue: tanh, encode, ONE fire-and-forget publish
    f32x4 accs = (acc4[0] + acc4[1]) + (acc4[2] + acc4[3]);
    unsigned long long hx = 0;
    #pragma unroll
    for (int r = 0; r < 4; ++r) {
      float zz = accs[r] + xwv[r];
      float e = __expf(2.0f * zz);
      float h = (e - 1.0f) / (e + 1.0f);
      union { _Float16 f; unsigned short u; } cv; cv.f = (_Float16)h;
      unsigned short u = (cv.u == 0x8000u) ? 0u : cv.u;
      hx |= (unsigned long long)(u ^ 0x8000u) << (16 * r);
    }
    __hip_atomic_store(hsx + (size_t)t * 16384 + pub_off, hx,
                       __ATOMIC_RELAXED, __HIP_MEMORY_SCOPE_AGENT);
  }
}

// ---------------- FC: out[b*512+t][1024] = concat(hf,hb)@Wfc^T + b (fp16 frag) ----
// t-major blocks: block = (t, ob); A-tile = h[t][all 64 b][64 k] read directly
// from the fragment-layout hs (contiguous 1 KB chunks), XOR-decoded.
__global__ __launch_bounds__(256, 4)
void fc_kernel(const unsigned long long* __restrict__ hsfF,
               const unsigned long long* __restrict__ hsfB,
               const short* __restrict__ wfcpack, const float* __restrict__ bfc,
               float* __restrict__ out)
{
  __shared__ unsigned long long Alds[1024];  // 8 KB [btl*2+ik][128]
  __shared__ short Blds[4096];               // 8 KB fp16 fragment-linear
  const int tid = threadIdx.x;
  const int lane = tid & 63;
  const int wv = tid >> 6;
  const int mt2 = wv & 1;
  const int nt2 = wv >> 1;
  const int t = blockIdx.x;
  const int ob = blockIdx.y;
  const int ik = tid >> 7;            // kt-local (0..1)
  const int btl = (tid >> 5) & 3;     // bt block
  const int w4 = (tid & 31) * 4;      // u64 offset within 128

  const i32x4 flip32 = {(int)0x80008000, (int)0x80008000,
                        (int)0x80008000, (int)0x80008000};
  f32x4 z = {0.f, 0.f, 0.f, 0.f};
  f32x4 acc[2][2] = {{z, z}, {z, z}};

  for (int kc = 0; kc < 32; ++kc) {
    {  // A-stage: 1024 u64 (64 b x 64 k), contiguous 32B per thread
      const unsigned long long* src =
          (kc < 16 ? hsfF : hsfB) + (size_t)t * 16384;
      int kt0 = (kc & 15) * 2;
      const unsigned long long* ap = src + btl * 4096 + (kt0 + ik) * 128 + w4;
      i32x4 a01 = *(const i32x4*)ap ^ flip32;
      i32x4 a23 = *(const i32x4*)(ap + 2) ^ flip32;
      *(i32x4*)&Alds[(btl * 2 + ik) * 128 + w4] = a01;
      *(i32x4*)&Alds[(btl * 2 + ik) * 128 + w4 + 2] = a23;
    }
    {  // B-stage: fragment-linear contiguous copy (2 x k32 blocks)
      const i32x4* src = (const i32x4*)(wfcpack + ((size_t)ob * 64 + kc * 2) * 2048);
      i32x4* dst = (i32x4*)Blds;
      dst[tid] = src[tid];
      dst[tid + 256] = src[tid + 256];
    }
    __syncthreads();
    #pragma unroll
    for (int k2 = 0; k2 < 2; ++k2) {
      f16x8 afr[2];
      #pragma unroll
      for (int mi = 0; mi < 2; ++mi) {
        int btm = mt2 * 2 + mi;
        u64x2 av;
        av[0] = Alds[(btm * 2 + k2) * 128 + lane];
        av[1] = Alds[(btm * 2 + k2) * 128 + 64 + lane];
        afr[mi] = __builtin_bit_cast(f16x8, av);
      }
      #pragma unroll
      for (int ni = 0; ni < 2; ++ni) {
        int ntg = nt2 * 2 + ni;
        f16x8 bfr = *(const f16x8*)((const char*)Blds + ((k2 * 4 + ntg) * 64 + lane) * 16);
        #pragma unroll
        for (int mi = 0; mi < 2; ++mi)
          acc[mi][ni] = __builtin_amdgcn_mfma_f32_16x16x32_f16(afr[mi], bfr, acc[mi][ni], 0, 0, 0);
      }
    }
    __syncthreads();
  }
  #pragma unroll
  for (int mi = 0; mi < 2; ++mi) {
    #pragma unroll
    for (int ni = 0; ni < 2; ++ni) {
      int o = ob * 64 + nt2 * 32 + ni * 16 + (lane & 15);
      float bias = bfc[o];
      #pragma unroll
      for (int r = 0; r < 4; ++r) {
        int b = mt2 * 32 + mi * 16 + (lane >> 4) * 4 + r;
        out[(size_t)(b * 512 + t) * O_ + o] = acc[mi][ni][r] + bias;
      }
    }
  }
}

extern "C" void kernel_launch(void* const* d_in, const int* in_sizes, int n_in,
                              void* d_out, int out_size, void* d_ws, size_t ws_size,
                              hipStream_t stream) {
  const int* x = (const int*)d_in[0];
  const float* WihF = (const float*)d_in[1];
  const float* WhhF = (const float*)d_in[2];
  const float* bihF = (const float*)d_in[3];
  const float* bhhF = (const float*)d_in[4];
  const float* WihB = (const float*)d_in[5];
  const float* WhhB = (const float*)d_in[6];
  const float* bihB = (const float*)d_in[7];
  const float* bhhB = (const float*)d_in[8];
  const float* Wfc  = (const float*)d_in[9];
  const float* bfc  = (const float*)d_in[10];
  float* out = (float*)d_out;
  char* ws = (char*)d_ws;

  float* tableF = (float*)(ws + OFF_TABLE_F);
  float* tableB = (float*)(ws + OFF_TABLE_B);
  int* xT = (int*)(ws + OFF_XT);
  short* whhpack = (short*)(ws + OFF_WHH);
  short* wfcpack = (short*)(ws + OFF_WFC);
  unsigned long long* hsfF = (unsigned long long*)(ws + OFF_HSF);
  unsigned long long* hsfB = (unsigned long long*)(ws + OFF_HSB);

  hipFuncSetAttribute((const void*)rnn_kernel,
                      hipFuncAttributeMaxDynamicSharedMemorySize, 131072);

  prep_kernel<<<dim3(2048), dim3(256), 0, stream>>>(
      x, WihF, WhhF, bihF, bhhF, WihB, WhhB, bihB, bhhB, Wfc,
      tableF, tableB, xT, whhpack, wfcpack, hsfF);
  rnn_kernel<<<dim3(128), dim3(256), 131072, stream>>>(
      xT, tableF, tableB, whhpack, hsfF, hsfB);
  fc_kernel<<<dim3(512, 16), dim3(256), 0, stream>>>(
      hsfF, hsfB, wfcpack, bfc, out);
}

// Round 10
// 1642.239 us; speedup vs baseline: 1.3958x; 1.3958x over previous
//
#include <hip/hip_runtime.h>
#include <math.h>

#define B_ 64
#define T_ 512
#define H_ 1024
#define V_ 256
#define O_ 1024
#define KFC 2048

typedef short bf16x8 __attribute__((ext_vector_type(8)));
typedef _Float16 f16x8 __attribute__((ext_vector_type(8)));
typedef float f32x4 __attribute__((ext_vector_type(4)));
typedef int   i32x4 __attribute__((ext_vector_type(4)));
typedef unsigned long long u64x2 __attribute__((ext_vector_type(2)));

#define FLIP64 0x8000800080008000ULL

// ---- workspace layout (bytes) ----
#define OFF_TABLE_F 0                 // [V][H] f32 (W_ih^T + b_ih + b_hh), fwd
#define OFF_TABLE_B 1048576           // same, bwd
#define OFF_XT      2097152           // [T][B] i32 (transposed x)
#define OFF_WHH     2228224           // fp16 [d][cs16][ct4][kt32][lane64][8] (4 MB)
#define OFF_WFC     6422528           // fp16 [ob][k32][nt][lane][8] (4 MB)
#define OFF_HSF     10616832          // fp16 frag, sign-flipped: [t][bt][kt][q][lane'] u64 (64 MB)
#define OFF_HSB     77725696          // same, bwd (64 MB)  — adjacent to HSF

__device__ __forceinline__ float fast_tanh(float zz) {
  float e = __expf(2.0f * zz);
  return 1.0f - 2.0f * __builtin_amdgcn_rcpf(e + 1.0f);
}

// ---------------- prep: tables, transposes, packed weights, hs zeroing ----------------
__global__ void prep_kernel(const int* __restrict__ x,
    const float* __restrict__ WihF, const float* __restrict__ WhhF,
    const float* __restrict__ bihF, const float* __restrict__ bhhF,
    const float* __restrict__ WihB, const float* __restrict__ WhhB,
    const float* __restrict__ bihB, const float* __restrict__ bhhB,
    const float* __restrict__ Wfc,
    float* __restrict__ tableF, float* __restrict__ tableB,
    int* __restrict__ xT, short* __restrict__ whhpack,
    short* __restrict__ wfcpack, unsigned long long* __restrict__ hsz)
{
  const long NT1 = 524288, NT2 = 32768, NT3 = 2097152, NT4 = 2097152;
  const long NT5 = 16777216;  // zero hsF+hsB (adjacent, 128 MB) as u64
  const long total = NT1 + NT2 + NT3 + NT4 + NT5;
  for (long i = (long)blockIdx.x * blockDim.x + threadIdx.x; i < total;
       i += (long)gridDim.x * blockDim.x) {
    long j = i;
    if (j < NT1) {
      int d = (int)(j >> 18);
      int r = (int)(j & 262143);
      int v = r >> 10, h = r & 1023;
      const float* Wih = d ? WihB : WihF;
      const float* bi  = d ? bihB : bihF;
      const float* bh  = d ? bhhB : bhhF;
      (d ? tableB : tableF)[r] = Wih[h * V_ + v] + bi[h] + bh[h];
      continue;
    }
    j -= NT1;
    if (j < NT2) {
      int t = (int)(j >> 6), bb = (int)(j & 63);
      xT[j] = x[bb * T_ + t];
      continue;
    }
    j -= NT2;
    if (j < NT3) {
      // whhpack [d][cs16][ct4][kt32][lane64][8]:
      //   c = cs*64 + ct*16 + (lane&15), k = kt*32 + (lane>>4)*8 + jj
      int d = (int)(j >> 20);
      int r = (int)(j & 1048575);
      int jj = r & 7;
      int lanei = (r >> 3) & 63;
      int kt = (r >> 9) & 31;
      int cti = (r >> 14) & 3;
      int csi = (r >> 16) & 15;
      int c = csi * 64 + cti * 16 + (lanei & 15);
      int k = kt * 32 + (lanei >> 4) * 8 + jj;
      float w = (d ? WhhB : WhhF)[c * H_ + k];
      _Float16 wh = (_Float16)w;
      whhpack[j] = __builtin_bit_cast(short, wh);
      continue;
    }
    j -= NT3;
    if (j < NT4) {
      int jj = (int)(j & 7);
      int lanei = (int)((j >> 3) & 63);
      int nti = (int)((j >> 9) & 3);
      int k32 = (int)((j >> 11) & 63);
      int obi = (int)(j >> 17);
      int o = obi * 64 + nti * 16 + (lanei & 15);
      int k = k32 * 32 + (lanei >> 4) * 8 + jj;
      _Float16 wf = (_Float16)Wfc[(long)o * KFC + k];
      wfcpack[j] = __builtin_bit_cast(short, wf);
      continue;
    }
    j -= NT4;
    hsz[j] = 0ULL;  // unwritten sentinel for the self-signaling exchange
    continue;
  }
}

// ---------------- persistent bidirectional recurrence ----------------
// 128 WGs x 256 thr. WG = (dir, bt 16-row tile, cs 64-col slice); wave = ct.
// R8 structure (self-signaling exchange + cooperative dedup LDS staging) with
// HALF-SPLIT PIPELINED staging: both 8-u64 batches issued up front; raw
// s_barrier (lgkmcnt only — batch1 loads stay in flight across it); MFMA on
// kt0-15 hides batch1's L3 RTT; then poll/stage/MFMA kt16-31. No vmcnt(0)
// drains anywhere in the step loop.
__global__ __launch_bounds__(256, 1)
void rnn_kernel(const int* __restrict__ xT,
                const float* __restrict__ tableF, const float* __restrict__ tableB,
                const short* __restrict__ whhpack,
                unsigned long long* __restrict__ hsfF,
                unsigned long long* __restrict__ hsfB)
{
  extern __shared__ char lds[];
  char* ldsW = lds;               // 128 KB [ct][kt][lane][16B]
  char* ldsH = lds + 131072;      // 32 KB  [kt][q][lane] u64 (decoded h)
  const int tid = threadIdx.x;
  const int wg = blockIdx.x;
  const int dir = wg >> 6;
  const int bt = (wg >> 4) & 3;
  const int cs = wg & 15;
  const int lane = tid & 63;
  const int ct = tid >> 6;
  const int row = bt * 16 + (lane & 15);               // my batch row
  const int c4 = cs * 64 + ct * 16 + (lane >> 4) * 4;  // my 4 output cols
  const float* table = dir ? tableB : tableF;
  unsigned long long* hsx = dir ? hsfB : hsfF;
  const int pub_off = bt * 4096 + (c4 >> 5) * 128 + ((c4 >> 2) & 1) * 64 +
                      (lane & 15) + ((c4 >> 3) & 3) * 16;

  // one-time: W slice (my 64 cols) -> LDS, fragment-linear
  {
    const i32x4* wsrc = (const i32x4*)whhpack + (size_t)(dir * 16 + cs) * 8192;
    i32x4* wdst = (i32x4*)ldsW;
    #pragma unroll
    for (int it = 0; it < 32; ++it)
      wdst[it * 256 + tid] = wsrc[it * 256 + tid];
  }
  __syncthreads();

  const f32x4 zv = {0.f, 0.f, 0.f, 0.f};

  // ---- prologue: step 0 (h_0 = tanh(xw)) ----
  {
    int t0 = dir ? 511 : 0;
    int v = xT[t0 * 64 + row];
    f32x4 xwv = *(const f32x4*)(table + v * 1024 + c4);
    unsigned long long hx = 0;
    #pragma unroll
    for (int r = 0; r < 4; ++r) {
      float h = fast_tanh(xwv[r]);
      union { _Float16 f; unsigned short u; } cv; cv.f = (_Float16)h;
      unsigned short u = (cv.u == 0x8000u) ? 0u : cv.u;  // -0 -> +0
      hx |= (unsigned long long)(u ^ 0x8000u) << (16 * r);  // field never 0
    }
    __hip_atomic_store(hsx + (size_t)t0 * 16384 + pub_off, hx,
                       __ATOMIC_RELAXED, __HIP_MEMORY_SCOPE_AGENT);
  }

#define LDX(p) __hip_atomic_load((p), __ATOMIC_RELAXED, __HIP_MEMORY_SCOPE_AGENT)

  for (int s = 1; s < 512; ++s) {
    const int t = dir ? (511 - s) : s;
    const int tprev = dir ? (t + 1) : (t - 1);
    // xw gather early (independent; hides under poll)
    int v = xT[t * 64 + row];
    f32x4 xwv = *(const f32x4*)(table + v * 1024 + c4);

    // my 16 staged words of h_{s-1}; batch0 = jj 0..3 (kt 0..15),
    // batch1 = jj 4..7 (kt 16..31). Issue BOTH before polling batch0.
    const unsigned long long* sp =
        hsx + (size_t)tprev * 16384 + bt * 4096 + tid * 2;
    unsigned long long a0[4], b0[4], a1[4], b1[4];
    #pragma unroll
    for (int i = 0; i < 4; ++i) {
      a0[i] = LDX(sp + i * 512);
      b0[i] = LDX(sp + i * 512 + 1);
    }
    #pragma unroll
    for (int i = 0; i < 4; ++i) {
      a1[i] = LDX(sp + (4 + i) * 512);
      b1[i] = LDX(sp + (4 + i) * 512 + 1);
    }

    // poll batch0 (nonzero == written)
    for (;;) {
      int miss = 0;
      #pragma unroll
      for (int i = 0; i < 4; ++i)
        miss |= (a0[i] == 0ULL) | (b0[i] == 0ULL);
      if (!__ballot(miss)) break;
      __builtin_amdgcn_s_sleep(1);
      #pragma unroll
      for (int i = 0; i < 4; ++i) {
        a0[i] = LDX(sp + i * 512);
        b0[i] = LDX(sp + i * 512 + 1);
      }
    }
    // stage batch0 (decode) -> ldsH kt 0..15
    #pragma unroll
    for (int jj = 0; jj < 4; ++jj) {
      u64x2 w; w[0] = a0[jj] ^ FLIP64; w[1] = b0[jj] ^ FLIP64;
      *(u64x2*)(ldsH + jj * 4096 + tid * 16) = w;
    }
    // raw barrier: drain LDS writes only — batch1 loads stay in flight
    asm volatile("s_waitcnt lgkmcnt(0)" ::: "memory");
    __builtin_amdgcn_s_barrier();
    asm volatile("" ::: "memory");

    f32x4 acc4[4] = {zv, zv, zv, zv};
    #pragma unroll
    for (int kt = 0; kt < 16; ++kt) {   // hides batch1's L3 RTT
      f16x8 af = *(const f16x8*)(ldsW + ((ct * 32 + kt) * 64 + lane) * 16);
      u64x2 bv;
      bv[0] = *(const unsigned long long*)(ldsH + (kt * 128 + lane) * 8);
      bv[1] = *(const unsigned long long*)(ldsH + (kt * 128 + 64 + lane) * 8);
      f16x8 bf = __builtin_bit_cast(f16x8, bv);
      acc4[kt & 3] =
          __builtin_amdgcn_mfma_f32_16x16x32_f16(af, bf, acc4[kt & 3], 0, 0, 0);
    }

    // poll batch1 (usually already nonzero)
    for (;;) {
      int miss = 0;
      #pragma unroll
      for (int i = 0; i < 4; ++i)
        miss |= (a1[i] == 0ULL) | (b1[i] == 0ULL);
      if (!__ballot(miss)) break;
      __builtin_amdgcn_s_sleep(1);
      #pragma unroll
      for (int i = 0; i < 4; ++i) {
        a1[i] = LDX(sp + (4 + i) * 512);
        b1[i] = LDX(sp + (4 + i) * 512 + 1);
      }
    }
    // stage batch1 -> ldsH kt 16..31
    #pragma unroll
    for (int jj = 0; jj < 4; ++jj) {
      u64x2 w; w[0] = a1[jj] ^ FLIP64; w[1] = b1[jj] ^ FLIP64;
      *(u64x2*)(ldsH + (4 + jj) * 4096 + tid * 16) = w;
    }
    asm volatile("s_waitcnt lgkmcnt(0)" ::: "memory");
    __builtin_amdgcn_s_barrier();
    asm volatile("" ::: "memory");

    #pragma unroll
    for (int kt = 16; kt < 32; ++kt) {
      f16x8 af = *(const f16x8*)(ldsW + ((ct * 32 + kt) * 64 + lane) * 16);
      u64x2 bv;
      bv[0] = *(const unsigned long long*)(ldsH + (kt * 128 + lane) * 8);
      bv[1] = *(const unsigned long long*)(ldsH + (kt * 128 + 64 + lane) * 8);
      f16x8 bf = __builtin_bit_cast(f16x8, bv);
      acc4[kt & 3] =
          __builtin_amdgcn_mfma_f32_16x16x32_f16(af, bf, acc4[kt & 3], 0, 0, 0);
    }

    // epilogue: tanh, encode, ONE fire-and-forget publish
    f32x4 accs = (acc4[0] + acc4[1]) + (acc4[2] + acc4[3]);
    unsigned long long hx = 0;
    #pragma unroll
    for (int r = 0; r < 4; ++r) {
      float h = fast_tanh(accs[r] + xwv[r]);
      union { _Float16 f; unsigned short u; } cv; cv.f = (_Float16)h;
      unsigned short u = (cv.u == 0x8000u) ? 0u : cv.u;
      hx |= (unsigned long long)(u ^ 0x8000u) << (16 * r);
    }
    __hip_atomic_store(hsx + (size_t)t * 16384 + pub_off, hx,
                       __ATOMIC_RELAXED, __HIP_MEMORY_SCOPE_AGENT);
  }
#undef LDX
}

// ---------------- FC: out[b*512+t][1024] = concat(hf,hb)@Wfc^T + b (fp16 frag) ----
// t-major blocks: block = (t, ob); A-tile = h[t][all 64 b][64 k] read directly
// from the fragment-layout hs (contiguous 1 KB chunks), XOR-decoded.
__global__ __launch_bounds__(256, 4)
void fc_kernel(const unsigned long long* __restrict__ hsfF,
               const unsigned long long* __restrict__ hsfB,
               const short* __restrict__ wfcpack, const float* __restrict__ bfc,
               float* __restrict__ out)
{
  __shared__ unsigned long long Alds[1024];  // 8 KB [btl*2+ik][128]
  __shared__ short Blds[4096];               // 8 KB fp16 fragment-linear
  const int tid = threadIdx.x;
  const int lane = tid & 63;
  const int wv = tid >> 6;
  const int mt2 = wv & 1;
  const int nt2 = wv >> 1;
  const int t = blockIdx.x;
  const int ob = blockIdx.y;
  const int ik = tid >> 7;            // kt-local (0..1)
  const int btl = (tid >> 5) & 3;     // bt block
  const int w4 = (tid & 31) * 4;      // u64 offset within 128

  const i32x4 flip32 = {(int)0x80008000, (int)0x80008000,
                        (int)0x80008000, (int)0x80008000};
  f32x4 z = {0.f, 0.f, 0.f, 0.f};
  f32x4 acc[2][2] = {{z, z}, {z, z}};

  for (int kc = 0; kc < 32; ++kc) {
    {  // A-stage: 1024 u64 (64 b x 64 k), contiguous 32B per thread
      const unsigned long long* src =
          (kc < 16 ? hsfF : hsfB) + (size_t)t * 16384;
      int kt0 = (kc & 15) * 2;
      const unsigned long long* ap = src + btl * 4096 + (kt0 + ik) * 128 + w4;
      i32x4 a01 = *(const i32x4*)ap ^ flip32;
      i32x4 a23 = *(const i32x4*)(ap + 2) ^ flip32;
      *(i32x4*)&Alds[(btl * 2 + ik) * 128 + w4] = a01;
      *(i32x4*)&Alds[(btl * 2 + ik) * 128 + w4 + 2] = a23;
    }
    {  // B-stage: fragment-linear contiguous copy (2 x k32 blocks)
      const i32x4* src = (const i32x4*)(wfcpack + ((size_t)ob * 64 + kc * 2) * 2048);
      i32x4* dst = (i32x4*)Blds;
      dst[tid] = src[tid];
      dst[tid + 256] = src[tid + 256];
    }
    __syncthreads();
    #pragma unroll
    for (int k2 = 0; k2 < 2; ++k2) {
      f16x8 afr[2];
      #pragma unroll
      for (int mi = 0; mi < 2; ++mi) {
        int btm = mt2 * 2 + mi;
        u64x2 av;
        av[0] = Alds[(btm * 2 + k2) * 128 + lane];
        av[1] = Alds[(btm * 2 + k2) * 128 + 64 + lane];
        afr[mi] = __builtin_bit_cast(f16x8, av);
      }
      #pragma unroll
      for (int ni = 0; ni < 2; ++ni) {
        int ntg = nt2 * 2 + ni;
        f16x8 bfr = *(const f16x8*)((const char*)Blds + ((k2 * 4 + ntg) * 64 + lane) * 16);
        #pragma unroll
        for (int mi = 0; mi < 2; ++mi)
          acc[mi][ni] = __builtin_amdgcn_mfma_f32_16x16x32_f16(afr[mi], bfr, acc[mi][ni], 0, 0, 0);
      }
    }
    __syncthreads();
  }
  #pragma unroll
  for (int mi = 0; mi < 2; ++mi) {
    #pragma unroll
    for (int ni = 0; ni < 2; ++ni) {
      int o = ob * 64 + nt2 * 32 + ni * 16 + (lane & 15);
      float bias = bfc[o];
      #pragma unroll
      for (int r = 0; r < 4; ++r) {
        int b = mt2 * 32 + mi * 16 + (lane >> 4) * 4 + r;
        out[(size_t)(b * 512 + t) * O_ + o] = acc[mi][ni][r] + bias;
      }
    }
  }
}

extern "C" void kernel_launch(void* const* d_in, const int* in_sizes, int n_in,
                              void* d_out, int out_size, void* d_ws, size_t ws_size,
                              hipStream_t stream) {
  const int* x = (const int*)d_in[0];
  const float* WihF = (const float*)d_in[1];
  const float* WhhF = (const float*)d_in[2];
  const float* bihF = (const float*)d_in[3];
  const float* bhhF = (const float*)d_in[4];
  const float* WihB = (const float*)d_in[5];
  const float* WhhB = (const float*)d_in[6];
  const float* bihB = (const float*)d_in[7];
  const float* bhhB = (const float*)d_in[8];
  const float* Wfc  = (const float*)d_in[9];
  const float* bfc  = (const float*)d_in[10];
  float* out = (float*)d_out;
  char* ws = (char*)d_ws;

  float* tableF = (float*)(ws + OFF_TABLE_F);
  float* tableB = (float*)(ws + OFF_TABLE_B);
  int* xT = (int*)(ws + OFF_XT);
  short* whhpack = (short*)(ws + OFF_WHH);
  short* wfcpack = (short*)(ws + OFF_WFC);
  unsigned long long* hsfF = (unsigned long long*)(ws + OFF_HSF);
  unsigned long long* hsfB = (unsigned long long*)(ws + OFF_HSB);

  hipFuncSetAttribute((const void*)rnn_kernel,
                      hipFuncAttributeMaxDynamicSharedMemorySize, 163840);

  prep_kernel<<<dim3(2048), dim3(256), 0, stream>>>(
      x, WihF, WhhF, bihF, bhhF, WihB, WhhB, bihB, bhhB, Wfc,
      tableF, tableB, xT, whhpack, wfcpack, hsfF);
  rnn_kernel<<<dim3(128), dim3(256), 163840, stream>>>(
      xT, tableF, tableB, whhpack, hsfF, hsfB);
  fc_kernel<<<dim3(512, 16), dim3(256), 0, stream>>>(
      hsfF, hsfB, wfcpack, bfc, out);
}

// Round 12
// 1553.039 us; speedup vs baseline: 1.4759x; 1.0574x over previous
//
#include <hip/hip_runtime.h>
#include <math.h>

#define B_ 64
#define T_ 512
#define H_ 1024
#define V_ 256
#define O_ 1024
#define KFC 2048

typedef short bf16x8 __attribute__((ext_vector_type(8)));
typedef _Float16 f16x8 __attribute__((ext_vector_type(8)));
typedef float f32x4 __attribute__((ext_vector_type(4)));
typedef int   i32x4 __attribute__((ext_vector_type(4)));
typedef unsigned long long u64x2 __attribute__((ext_vector_type(2)));

#define FLIP64 0x8000800080008000ULL

// ---- workspace layout (bytes) ----
#define OFF_TABLE_F 0                 // [V][H] f32 (W_ih^T + b_ih + b_hh), fwd
#define OFF_TABLE_B 1048576           // same, bwd
#define OFF_XT      2097152           // [T][B] i32 (transposed x)
#define OFF_WHH     2228224           // fp16 [d][cs16][ct4][kt32][lane64][8] (4 MB)
#define OFF_WFC     6422528           // fp16 [ob][k32][nt][lane][8] (4 MB)
#define OFF_HSF     10616832          // fp16 frag, sign-flipped: [t][bt][kt][q][lane'] u64 (64 MB)
#define OFF_HSB     77725696          // same, bwd (64 MB)  — adjacent to HSF

__device__ __forceinline__ float fast_tanh(float zz) {
  float e = __expf(2.0f * zz);
  return 1.0f - 2.0f * __builtin_amdgcn_rcpf(e + 1.0f);
}

// ---------------- prep: tables, transposes, packed weights, hs zeroing ----------------
__global__ void prep_kernel(const int* __restrict__ x,
    const float* __restrict__ WihF, const float* __restrict__ WhhF,
    const float* __restrict__ bihF, const float* __restrict__ bhhF,
    const float* __restrict__ WihB, const float* __restrict__ WhhB,
    const float* __restrict__ bihB, const float* __restrict__ bhhB,
    const float* __restrict__ Wfc,
    float* __restrict__ tableF, float* __restrict__ tableB,
    int* __restrict__ xT, short* __restrict__ whhpack,
    short* __restrict__ wfcpack, unsigned long long* __restrict__ hsz)
{
  const long NT1 = 524288, NT2 = 32768, NT3 = 2097152, NT4 = 2097152;
  const long NT5 = 16777216;  // zero hsF+hsB (adjacent, 128 MB) as u64
  const long total = NT1 + NT2 + NT3 + NT4 + NT5;
  for (long i = (long)blockIdx.x * blockDim.x + threadIdx.x; i < total;
       i += (long)gridDim.x * blockDim.x) {
    long j = i;
    if (j < NT1) {
      int d = (int)(j >> 18);
      int r = (int)(j & 262143);
      int v = r >> 10, h = r & 1023;
      const float* Wih = d ? WihB : WihF;
      const float* bi  = d ? bihB : bihF;
      const float* bh  = d ? bhhB : bhhF;
      (d ? tableB : tableF)[r] = Wih[h * V_ + v] + bi[h] + bh[h];
      continue;
    }
    j -= NT1;
    if (j < NT2) {
      int t = (int)(j >> 6), bb = (int)(j & 63);
      xT[j] = x[bb * T_ + t];
      continue;
    }
    j -= NT2;
    if (j < NT3) {
      // whhpack [d][cs16][ct4][kt32][lane64][8]:
      //   c = cs*64 + ct*16 + (lane&15), k = kt*32 + (lane>>4)*8 + jj
      int d = (int)(j >> 20);
      int r = (int)(j & 1048575);
      int jj = r & 7;
      int lanei = (r >> 3) & 63;
      int kt = (r >> 9) & 31;
      int cti = (r >> 14) & 3;
      int csi = (r >> 16) & 15;
      int c = csi * 64 + cti * 16 + (lanei & 15);
      int k = kt * 32 + (lanei >> 4) * 8 + jj;
      float w = (d ? WhhB : WhhF)[c * H_ + k];
      _Float16 wh = (_Float16)w;
      whhpack[j] = __builtin_bit_cast(short, wh);
      continue;
    }
    j -= NT3;
    if (j < NT4) {
      int jj = (int)(j & 7);
      int lanei = (int)((j >> 3) & 63);
      int nti = (int)((j >> 9) & 3);
      int k32 = (int)((j >> 11) & 63);
      int obi = (int)(j >> 17);
      int o = obi * 64 + nti * 16 + (lanei & 15);
      int k = k32 * 32 + (lanei >> 4) * 8 + jj;
      _Float16 wf = (_Float16)Wfc[(long)o * KFC + k];
      wfcpack[j] = __builtin_bit_cast(short, wf);
      continue;
    }
    j -= NT4;
    hsz[j] = 0ULL;  // unwritten sentinel for the self-signaling exchange
    continue;
  }
}

// ---------------- persistent bidirectional recurrence ----------------
// 128 WGs x 256 thr. WG = (dir, bt 16-row tile, cs 64-col slice); wave = ct.
// W slice held ENTIRELY IN VGPRs (32 x f16x8 = 128 regs/lane, loaded once):
// zero LDS traffic for the A-operand. h exchange: self-signaling fp16
// fragment slots in hs (u64 nonzero == written), cooperative dedup staging
// into 32 KB LDS, half-split pipelined with raw lgkm-only barriers.
__global__ __launch_bounds__(256, 1)
void rnn_kernel(const int* __restrict__ xT,
                const float* __restrict__ tableF, const float* __restrict__ tableB,
                const short* __restrict__ whhpack,
                unsigned long long* __restrict__ hsfF,
                unsigned long long* __restrict__ hsfB)
{
  extern __shared__ char lds[];   // 32 KB: ldsH [kt][q][lane] u64 (decoded h)
  char* ldsH = lds;
  const int tid = threadIdx.x;
  const int wg = blockIdx.x;
  const int dir = wg >> 6;
  const int bt = (wg >> 4) & 3;
  const int cs = wg & 15;
  const int lane = tid & 63;
  const int ct = tid >> 6;
  const int row = bt * 16 + (lane & 15);               // my batch row
  const int c4 = cs * 64 + ct * 16 + (lane >> 4) * 4;  // my 4 output cols
  const float* table = dir ? tableB : tableF;
  unsigned long long* hsx = dir ? hsfB : hsfF;
  const int pub_off = bt * 4096 + (c4 >> 5) * 128 + ((c4 >> 2) & 1) * 64 +
                      (lane & 15) + ((c4 >> 3) & 3) * 16;

  // one-time: W slice -> REGISTERS (fragment-linear, literal indices only)
  f16x8 Wreg[32];
  {
    const i32x4* wsrc = (const i32x4*)whhpack + (size_t)(dir * 16 + cs) * 8192;
    #pragma unroll
    for (int kt = 0; kt < 32; ++kt)
      Wreg[kt] = __builtin_bit_cast(f16x8, wsrc[(ct * 32 + kt) * 64 + lane]);
  }

  const f32x4 zv = {0.f, 0.f, 0.f, 0.f};

  // ---- prologue: step 0 (h_0 = tanh(xw)) ----
  {
    int t0 = dir ? 511 : 0;
    int v = xT[t0 * 64 + row];
    f32x4 xwv = *(const f32x4*)(table + v * 1024 + c4);
    unsigned long long hx = 0;
    #pragma unroll
    for (int r = 0; r < 4; ++r) {
      float h = fast_tanh(xwv[r]);
      union { _Float16 f; unsigned short u; } cv; cv.f = (_Float16)h;
      unsigned short u = (cv.u == 0x8000u) ? 0u : cv.u;  // -0 -> +0
      hx |= (unsigned long long)(u ^ 0x8000u) << (16 * r);  // field never 0
    }
    __hip_atomic_store(hsx + (size_t)t0 * 16384 + pub_off, hx,
                       __ATOMIC_RELAXED, __HIP_MEMORY_SCOPE_AGENT);
  }

#define LDX(p) __hip_atomic_load((p), __ATOMIC_RELAXED, __HIP_MEMORY_SCOPE_AGENT)

  for (int s = 1; s < 512; ++s) {
    const int t = dir ? (511 - s) : s;
    const int tprev = dir ? (t + 1) : (t - 1);
    // xw gather early (independent; hides under poll)
    int v = xT[t * 64 + row];
    f32x4 xwv = *(const f32x4*)(table + v * 1024 + c4);

    // my 16 staged words of h_{s-1}; batch0 = jj 0..3 (kt 0..15),
    // batch1 = jj 4..7 (kt 16..31). Issue BOTH before polling batch0.
    const unsigned long long* sp =
        hsx + (size_t)tprev * 16384 + bt * 4096 + tid * 2;
    unsigned long long a0[4], b0[4], a1[4], b1[4];
    #pragma unroll
    for (int i = 0; i < 4; ++i) {
      a0[i] = LDX(sp + i * 512);
      b0[i] = LDX(sp + i * 512 + 1);
    }
    #pragma unroll
    for (int i = 0; i < 4; ++i) {
      a1[i] = LDX(sp + (4 + i) * 512);
      b1[i] = LDX(sp + (4 + i) * 512 + 1);
    }

    // poll batch0 (nonzero == written)
    for (;;) {
      int miss = 0;
      #pragma unroll
      for (int i = 0; i < 4; ++i)
        miss |= (a0[i] == 0ULL) | (b0[i] == 0ULL);
      if (!__ballot(miss)) break;
      __builtin_amdgcn_s_sleep(1);
      #pragma unroll
      for (int i = 0; i < 4; ++i) {
        a0[i] = LDX(sp + i * 512);
        b0[i] = LDX(sp + i * 512 + 1);
      }
    }
    // stage batch0 (decode) -> ldsH kt 0..15
    #pragma unroll
    for (int jj = 0; jj < 4; ++jj) {
      u64x2 w; w[0] = a0[jj] ^ FLIP64; w[1] = b0[jj] ^ FLIP64;
      *(u64x2*)(ldsH + jj * 4096 + tid * 16) = w;
    }
    // raw barrier: drain LDS writes only — batch1 loads stay in flight
    asm volatile("s_waitcnt lgkmcnt(0)" ::: "memory");
    __builtin_amdgcn_s_barrier();
    asm volatile("" ::: "memory");

    f32x4 acc4[4] = {zv, zv, zv, zv};
    #pragma unroll
    for (int kt = 0; kt < 16; ++kt) {   // hides batch1's L3 RTT
      u64x2 bv;
      bv[0] = *(const unsigned long long*)(ldsH + (kt * 128 + lane) * 8);
      bv[1] = *(const unsigned long long*)(ldsH + (kt * 128 + 64 + lane) * 8);
      f16x8 bf = __builtin_bit_cast(f16x8, bv);
      acc4[kt & 3] =
          __builtin_amdgcn_mfma_f32_16x16x32_f16(Wreg[kt], bf, acc4[kt & 3], 0, 0, 0);
    }

    // poll batch1 (usually already nonzero)
    for (;;) {
      int miss = 0;
      #pragma unroll
      for (int i = 0; i < 4; ++i)
        miss |= (a1[i] == 0ULL) | (b1[i] == 0ULL);
      if (!__ballot(miss)) break;
      __builtin_amdgcn_s_sleep(1);
      #pragma unroll
      for (int i = 0; i < 4; ++i) {
        a1[i] = LDX(sp + (4 + i) * 512);
        b1[i] = LDX(sp + (4 + i) * 512 + 1);
      }
    }
    // stage batch1 -> ldsH kt 16..31
    #pragma unroll
    for (int jj = 0; jj < 4; ++jj) {
      u64x2 w; w[0] = a1[jj] ^ FLIP64; w[1] = b1[jj] ^ FLIP64;
      *(u64x2*)(ldsH + (4 + jj) * 4096 + tid * 16) = w;
    }
    asm volatile("s_waitcnt lgkmcnt(0)" ::: "memory");
    __builtin_amdgcn_s_barrier();
    asm volatile("" ::: "memory");

    #pragma unroll
    for (int kt = 16; kt < 32; ++kt) {
      u64x2 bv;
      bv[0] = *(const unsigned long long*)(ldsH + (kt * 128 + lane) * 8);
      bv[1] = *(const unsigned long long*)(ldsH + (kt * 128 + 64 + lane) * 8);
      f16x8 bf = __builtin_bit_cast(f16x8, bv);
      acc4[kt & 3] =
          __builtin_amdgcn_mfma_f32_16x16x32_f16(Wreg[kt], bf, acc4[kt & 3], 0, 0, 0);
    }

    // epilogue: tanh, encode, ONE fire-and-forget publish
    f32x4 accs = (acc4[0] + acc4[1]) + (acc4[2] + acc4[3]);
    unsigned long long hx = 0;
    #pragma unroll
    for (int r = 0; r < 4; ++r) {
      float h = fast_tanh(accs[r] + xwv[r]);
      union { _Float16 f; unsigned short u; } cv; cv.f = (_Float16)h;
      unsigned short u = (cv.u == 0x8000u) ? 0u : cv.u;
      hx |= (unsigned long long)(u ^ 0x8000u) << (16 * r);
    }
    __hip_atomic_store(hsx + (size_t)t * 16384 + pub_off, hx,
                       __ATOMIC_RELAXED, __HIP_MEMORY_SCOPE_AGENT);
  }
#undef LDX
}

// ---------------- FC: out[b*512+t][1024] = concat(hf,hb)@Wfc^T + b (fp16 frag) ----
// Block = (4 consecutive t, ob); wave w owns t = 4*bx + w (64 rows x 64 cols,
// identical fragment formulas as the verified per-t version with btm=mi,
// ntg=ni). FIX vs R11: stage the FULL tile — 16 u64/lane (4 x i32x4 per
// kt-row x 2 rows), not 8.
__global__ __launch_bounds__(256, 2)
void fc_kernel(const unsigned long long* __restrict__ hsfF,
               const unsigned long long* __restrict__ hsfB,
               const short* __restrict__ wfcpack, const float* __restrict__ bfc,
               float* __restrict__ out)
{
  __shared__ unsigned long long Alds[4096];  // 32 KB [w4][btl*2+rr][128]
  __shared__ short Blds[4096];               // 8 KB fp16 fragment-linear
  const int tid = threadIdx.x;
  const int lane = tid & 63;
  const int w = tid >> 6;            // wave = t-local
  const int t = blockIdx.x * 4 + w;
  const int ob = blockIdx.y;
  const int btl = lane >> 4;         // bt block staged by this lane
  const int li = lane & 15;

  const i32x4 flip32 = {(int)0x80008000, (int)0x80008000,
                        (int)0x80008000, (int)0x80008000};
  f32x4 z = {0.f, 0.f, 0.f, 0.f};
  f32x4 acc[4][4] = {{z, z, z, z}, {z, z, z, z}, {z, z, z, z}, {z, z, z, z}};
  unsigned long long* Aw = &Alds[w * 1024];

  for (int kc = 0; kc < 32; ++kc) {
    {  // A-stage: each wave stages its own t (1024 u64 = 8 KB), 16 u64/lane
      const unsigned long long* src =
          (kc < 16 ? hsfF : hsfB) + (size_t)t * 16384;
      int kt0 = (kc & 15) * 2;
      const unsigned long long* ap = src + btl * 4096 + kt0 * 128 + li * 8;
      #pragma unroll
      for (int rr = 0; rr < 2; ++rr) {
        i32x4 q0 = *(const i32x4*)(ap + rr * 128) ^ flip32;
        i32x4 q1 = *(const i32x4*)(ap + rr * 128 + 2) ^ flip32;
        i32x4 q2 = *(const i32x4*)(ap + rr * 128 + 4) ^ flip32;
        i32x4 q3 = *(const i32x4*)(ap + rr * 128 + 6) ^ flip32;
        unsigned long long* dst = &Aw[(btl * 2 + rr) * 128 + li * 8];
        *(i32x4*)(dst) = q0;
        *(i32x4*)(dst + 2) = q1;
        *(i32x4*)(dst + 4) = q2;
        *(i32x4*)(dst + 6) = q3;
      }
    }
    {  // B-stage: fragment-linear contiguous copy (2 x k32 blocks)
      const i32x4* src = (const i32x4*)(wfcpack + ((size_t)ob * 64 + kc * 2) * 2048);
      i32x4* dst = (i32x4*)Blds;
      dst[tid] = src[tid];
      dst[tid + 256] = src[tid + 256];
    }
    __syncthreads();
    #pragma unroll
    for (int k2 = 0; k2 < 2; ++k2) {
      f16x8 afr[4];
      #pragma unroll
      for (int mi = 0; mi < 4; ++mi) {
        u64x2 av;
        av[0] = Aw[(mi * 2 + k2) * 128 + lane];
        av[1] = Aw[(mi * 2 + k2) * 128 + 64 + lane];
        afr[mi] = __builtin_bit_cast(f16x8, av);
      }
      #pragma unroll
      for (int ni = 0; ni < 4; ++ni) {
        f16x8 bfr = *(const f16x8*)((const char*)Blds + ((k2 * 4 + ni) * 64 + lane) * 16);
        #pragma unroll
        for (int mi = 0; mi < 4; ++mi)
          acc[mi][ni] = __builtin_amdgcn_mfma_f32_16x16x32_f16(afr[mi], bfr, acc[mi][ni], 0, 0, 0);
      }
    }
    __syncthreads();
  }
  #pragma unroll
  for (int mi = 0; mi < 4; ++mi) {
    #pragma unroll
    for (int ni = 0; ni < 4; ++ni) {
      int o = ob * 64 + ni * 16 + (lane & 15);
      float bias = bfc[o];
      #pragma unroll
      for (int r = 0; r < 4; ++r) {
        int b = mi * 16 + (lane >> 4) * 4 + r;
        out[(size_t)(b * 512 + t) * O_ + o] = acc[mi][ni][r] + bias;
      }
    }
  }
}

extern "C" void kernel_launch(void* const* d_in, const int* in_sizes, int n_in,
                              void* d_out, int out_size, void* d_ws, size_t ws_size,
                              hipStream_t stream) {
  const int* x = (const int*)d_in[0];
  const float* WihF = (const float*)d_in[1];
  const float* WhhF = (const float*)d_in[2];
  const float* bihF = (const float*)d_in[3];
  const float* bhhF = (const float*)d_in[4];
  const float* WihB = (const float*)d_in[5];
  const float* WhhB = (const float*)d_in[6];
  const float* bihB = (const float*)d_in[7];
  const float* bhhB = (const float*)d_in[8];
  const float* Wfc  = (const float*)d_in[9];
  const float* bfc  = (const float*)d_in[10];
  float* out = (float*)d_out;
  char* ws = (char*)d_ws;

  float* tableF = (float*)(ws + OFF_TABLE_F);
  float* tableB = (float*)(ws + OFF_TABLE_B);
  int* xT = (int*)(ws + OFF_XT);
  short* whhpack = (short*)(ws + OFF_WHH);
  short* wfcpack = (short*)(ws + OFF_WFC);
  unsigned long long* hsfF = (unsigned long long*)(ws + OFF_HSF);
  unsigned long long* hsfB = (unsigned long long*)(ws + OFF_HSB);

  hipFuncSetAttribute((const void*)rnn_kernel,
                      hipFuncAttributeMaxDynamicSharedMemorySize, 32768);

  prep_kernel<<<dim3(2048), dim3(256), 0, stream>>>(
      x, WihF, WhhF, bihF, bhhF, WihB, WhhB, bihB, bhhB, Wfc,
      tableF, tableB, xT, whhpack, wfcpack, hsfF);
  rnn_kernel<<<dim3(128), dim3(256), 32768, stream>>>(
      xT, tableF, tableB, whhpack, hsfF, hsfB);
  fc_kernel<<<dim3(128, 16), dim3(256), 0, stream>>>(
      hsfF, hsfB, wfcpack, bfc, out);
}